// Round 4
// baseline (320.920 us; speedup 1.0000x reference)
//
#include <hip/hip_runtime.h>

#define S_LEN 2048
#define DIM   2048
#define NH    16
#define NKV   4
#define HD    128
#define WIN   512
#define BATCH 2

typedef __bf16 bf16x8 __attribute__((ext_vector_type(8)));
typedef __bf16 bf16x4 __attribute__((ext_vector_type(4)));
typedef float  f32x4  __attribute__((ext_vector_type(4)));

union U8 { bf16x8 v; bf16x4 h[2]; };

__device__ inline void async_load16(const void* g, void* l) {
  __builtin_amdgcn_global_load_lds(
      (const __attribute__((address_space(1))) unsigned int*)g,
      (__attribute__((address_space(3))) unsigned int*)l, 16, 0, 0);
}

// ------------- merged preprocess: x cast | weight cast+perm | rope tables ----
__global__ __launch_bounds__(256) void preprocess_kernel(
    const float* __restrict__ x,
    const float* __restrict__ Wq, const float* __restrict__ Wk,
    const float* __restrict__ Wv, const float* __restrict__ Wo,
    __bf16* __restrict__ xb, __bf16* __restrict__ wqkv, __bf16* __restrict__ wob,
    float* __restrict__ cosT, float* __restrict__ sinT) {
  const int blk = blockIdx.x, tid = threadIdx.x;
  if (blk < 8192) {
    int i = blk * 256 + tid;  // x: 2097152 float4
    float4 v = ((const float4*)x)[i];
    bf16x4 o;
    o[0] = (__bf16)v.x; o[1] = (__bf16)v.y; o[2] = (__bf16)v.z; o[3] = (__bf16)v.w;
    ((bf16x4*)xb)[i] = o;
  } else if (blk < 18432) {
    int i = (blk - 8192) * 256 + tid;  // weights: 5120 rows x 512 float4
    int orow = i >> 9, c = i & 511;
    const float* src;
    __bf16* dst;
    long soff;
    if (orow < 2048) {
      int n = orow & 127;
      int sr = (orow & ~127) + ((n >> 5) << 4) + (n & 15) + (((n >> 4) & 1) << 6);
      src = Wq; soff = (long)sr * 512 + c; dst = wqkv + (long)orow * 2048;
    } else if (orow < 2560) {
      int lr = orow - 2048, n = lr & 127;
      int sr = (lr & ~127) + ((n >> 5) << 4) + (n & 15) + (((n >> 4) & 1) << 6);
      src = Wk; soff = (long)sr * 512 + c; dst = wqkv + (long)orow * 2048;
    } else if (orow < 3072) {
      src = Wv; soff = (long)(orow - 2560) * 512 + c; dst = wqkv + (long)orow * 2048;
    } else {
      src = Wo; soff = (long)(orow - 3072) * 512 + c; dst = wob + (long)(orow - 3072) * 2048;
    }
    float4 v = ((const float4*)src)[soff];
    bf16x4 o;
    o[0] = (__bf16)v.x; o[1] = (__bf16)v.y; o[2] = (__bf16)v.z; o[3] = (__bf16)v.w;
    ((bf16x4*)dst)[c] = o;
  } else {
    int idx = (blk - 18432) * 256 + tid;  // rope: 131072
    int s = idx >> 6, d = idx & 63;
    float f = (float)s * powf(10000.f, -(float)d * (1.f / 64.f));
    float sn, cs;
    sincosf(f, &sn, &cs);
    cosT[idx] = cs;
    sinT[idx] = sn;
  }
}

// ---------------- O-projection GEMM, single-barrier double-buffered ----------
__global__ __launch_bounds__(256) void gemm_bt(
    const __bf16* __restrict__ A, const __bf16* __restrict__ Bt,
    float* __restrict__ C, int M, int N, int K) {
  __shared__ __bf16 As[2][128 * 32];
  __shared__ __bf16 Bs[2][128 * 32];
  const int t = threadIdx.x;
  const int wid = t >> 6, lane = t & 63;
  const int quad = lane >> 4, l15 = lane & 15;
  const long m0 = (long)blockIdx.x * 128, n0 = (long)blockIdx.y * 128;
  const int wm = (wid >> 1) * 64, wn = (wid & 1) * 64;

  const __bf16* ga = A + (m0 + (t >> 2)) * (long)K + (t & 3) * 8;
  const __bf16* gb = Bt + (n0 + (t >> 2)) * (long)K + (t & 3) * 8;
  const long rstride = 64L * K;

  f32x4 zero = {0.f, 0.f, 0.f, 0.f};
  f32x4 acc[4][4];
#pragma unroll
  for (int i = 0; i < 4; ++i)
#pragma unroll
    for (int j = 0; j < 4; ++j) acc[i][j] = zero;

  // prologue stage buf0
  async_load16(ga, (char*)As[0] + wid * 1024);
  async_load16(ga + rstride, (char*)As[0] + 4096 + wid * 1024);
  async_load16(gb, (char*)Bs[0] + wid * 1024);
  async_load16(gb + rstride, (char*)Bs[0] + 4096 + wid * 1024);

  const int niter = K >> 5;
  for (int it = 0; it < niter; ++it) {
    __syncthreads();  // drains this wave's loads for buf it&1 (issued last iter)
    if (it + 1 < niter) {
      const int kn = (it + 1) << 5;
      const int nb = (it + 1) & 1;
      async_load16(ga + kn, (char*)As[nb] + wid * 1024);
      async_load16(ga + kn + rstride, (char*)As[nb] + 4096 + wid * 1024);
      async_load16(gb + kn, (char*)Bs[nb] + wid * 1024);
      async_load16(gb + kn + rstride, (char*)Bs[nb] + 4096 + wid * 1024);
    }
    const __bf16* as = As[it & 1];
    const __bf16* bs = Bs[it & 1];
    bf16x8 af[4], bfr[4];
#pragma unroll
    for (int i = 0; i < 4; ++i) {
      af[i] = *(const bf16x8*)(as + (wm + i * 16 + l15) * 32 + quad * 8);
      bfr[i] = *(const bf16x8*)(bs + (wn + i * 16 + l15) * 32 + quad * 8);
    }
#pragma unroll
    for (int i = 0; i < 4; ++i)
#pragma unroll
      for (int j = 0; j < 4; ++j)
        acc[i][j] = __builtin_amdgcn_mfma_f32_16x16x32_bf16(af[i], bfr[j], acc[i][j], 0, 0, 0);
  }

#pragma unroll
  for (int i = 0; i < 4; ++i)
#pragma unroll
    for (int j = 0; j < 4; ++j)
#pragma unroll
      for (int r = 0; r < 4; ++r)
        C[(m0 + wm + i * 16 + quad * 4 + r) * (long)N + n0 + wn + j * 16 + l15] = acc[i][j][r];
}

// -------- QKV GEMM (dbuf) + fused RMSNorm/RoPE/gain/V-transpose epilogue ----
__global__ __launch_bounds__(256) void gemm_qkv(
    const __bf16* __restrict__ A, const __bf16* __restrict__ Bt,
    const float* __restrict__ gain,
    const float* __restrict__ cosT, const float* __restrict__ sinT,
    __bf16* __restrict__ Qo, __bf16* __restrict__ Ko, __bf16* __restrict__ Vt) {
  __shared__ __bf16 As[2][128 * 32];
  __shared__ __bf16 Bs[2][128 * 32];
  const int K = 2048;
  const int t = threadIdx.x;
  const int wid = t >> 6, lane = t & 63;
  const int quad = lane >> 4, l15 = lane & 15;
  const long m0 = (long)blockIdx.x * 128, n0 = (long)blockIdx.y * 128;
  const int wm = (wid >> 1) * 64, wn = (wid & 1) * 64;

  const __bf16* ga = A + (m0 + (t >> 2)) * (long)K + (t & 3) * 8;
  const __bf16* gb = Bt + (n0 + (t >> 2)) * (long)K + (t & 3) * 8;
  const long rstride = 64L * K;

  f32x4 zero = {0.f, 0.f, 0.f, 0.f};
  f32x4 acc[4][4];
#pragma unroll
  for (int i = 0; i < 4; ++i)
#pragma unroll
    for (int j = 0; j < 4; ++j) acc[i][j] = zero;

  async_load16(ga, (char*)As[0] + wid * 1024);
  async_load16(ga + rstride, (char*)As[0] + 4096 + wid * 1024);
  async_load16(gb, (char*)Bs[0] + wid * 1024);
  async_load16(gb + rstride, (char*)Bs[0] + 4096 + wid * 1024);

  const int niter = K >> 5;  // 64 (even -> last compute uses buf1)
  for (int it = 0; it < niter; ++it) {
    __syncthreads();
    if (it + 1 < niter) {
      const int kn = (it + 1) << 5;
      const int nb = (it + 1) & 1;
      async_load16(ga + kn, (char*)As[nb] + wid * 1024);
      async_load16(ga + kn + rstride, (char*)As[nb] + 4096 + wid * 1024);
      async_load16(gb + kn, (char*)Bs[nb] + wid * 1024);
      async_load16(gb + kn + rstride, (char*)Bs[nb] + 4096 + wid * 1024);
    }
    const __bf16* as = As[it & 1];
    const __bf16* bs = Bs[it & 1];
    bf16x8 af[4], bfr[4];
#pragma unroll
    for (int i = 0; i < 4; ++i) {
      af[i] = *(const bf16x8*)(as + (wm + i * 16 + l15) * 32 + quad * 8);
      bfr[i] = *(const bf16x8*)(bs + (wn + i * 16 + l15) * 32 + quad * 8);
    }
#pragma unroll
    for (int i = 0; i < 4; ++i)
#pragma unroll
      for (int j = 0; j < 4; ++j)
        acc[i][j] = __builtin_amdgcn_mfma_f32_16x16x32_bf16(af[i], bfr[j], acc[i][j], 0, 0, 0);
  }

  const int by = blockIdx.y;
  const int srow0 = (int)(m0 & 2047);
  const int bb = (int)(m0 >> 11);

  if (by >= 20) {
    const int kvh = by - 20;
    __bf16* Vb = Vt + ((long)(bb * NKV + kvh)) * HD * S_LEN;
#pragma unroll
    for (int i = 0; i < 4; ++i)
#pragma unroll
      for (int j = 0; j < 4; ++j) {
        int d = wn + j * 16 + l15;
        int s0 = srow0 + wm + i * 16 + quad * 4;
        bf16x4 o;
#pragma unroll
        for (int r = 0; r < 4; ++r) o[r] = (__bf16)acc[i][j][r];
        *(bf16x4*)(Vb + (long)d * S_LEN + s0) = o;
      }
  } else {
    // sums scratch in As[0]: final compute used buf1, so As[0] is free
    float* sums = (float*)As;
#pragma unroll
    for (int i = 0; i < 4; ++i)
#pragma unroll
      for (int r = 0; r < 4; ++r) {
        float t2 = acc[i][0][r] * acc[i][0][r] + acc[i][1][r] * acc[i][1][r] +
                   acc[i][2][r] * acc[i][2][r] + acc[i][3][r] * acc[i][3][r];
#pragma unroll
        for (int off = 1; off < 16; off <<= 1) t2 += __shfl_xor(t2, off, 64);
        if (l15 == 0) sums[(wm + i * 16 + quad * 4 + r) * 2 + (wn >> 6)] = t2;
      }
    __syncthreads();

    float g;
    __bf16* base;
    if (by < 16) {
      g = gain[by] * 0.08838834764831845f;
      base = Qo + ((long)(bb * NH + by)) * S_LEN * HD;
    } else {
      g = 1.f;
      base = Ko + ((long)(bb * NKV + (by - 16))) * S_LEN * HD;
    }
#pragma unroll
    for (int i = 0; i < 4; ++i)
#pragma unroll
      for (int r = 0; r < 4; ++r) {
        int lrow = wm + i * 16 + quad * 4 + r;
        int srow = srow0 + lrow;
        float rs = rsqrtf((sums[lrow * 2] + sums[lrow * 2 + 1]) * (1.f / 128.f) +
                          1.1920928955078125e-07f);
#pragma unroll
        for (int a = 0; a < 2; ++a) {
          int dlow = (wn >> 1) + a * 16 + l15;
          float cv = cosT[srow * 64 + dlow];
          float sv = sinT[srow * 64 + dlow];
          float x1 = acc[i][2 * a][r] * rs;
          float x2 = acc[i][2 * a + 1][r] * rs;
          base[(long)srow * HD + wn + (2 * a) * 16 + l15] = (__bf16)((x1 * cv + x2 * sv) * g);
          base[(long)srow * HD + wn + (2 * a + 1) * 16 + l15] = (__bf16)((-x1 * sv + x2 * cv) * g);
        }
      }
  }
}

// --------- sliding-window GQA attention: S^T trick, 64 rows/wave, dbuf ------
// block = 2 waves x 64 q-rows = 128 rows; TK=32, double-buffered K/V staging,
// single barrier per tile. S^T = mfma(kf, qf) puts 4 CONSECUTIVE keys per lane
// reg-group -> packed b64 P-writes. PV uses verified 16x16x32 layouts.
__global__ __launch_bounds__(128, 1) void attn_kernel(
    const __bf16* __restrict__ Q,   // [B][NH][S][HD] (perm d, pre-scaled)
    const __bf16* __restrict__ K,   // [B][NKV][S][HD] (perm d)
    const __bf16* __restrict__ Vt,  // [B][NKV][HD][S] (true d)
    const float* __restrict__ gain,
    __bf16* __restrict__ Y) {       // [B][S][NH*HD]
  __shared__ __bf16 Ks[2][32 * 128];  // [key][d], 16B-chunk phys = logical ^ (key&15)
  __shared__ __bf16 Vs[2][128 * 32];  // [d][key], 16B-chunk phys = logical ^ (d&3)
  __shared__ __bf16 Ps[2][64 * 32];   // per-wave P [q][key], 8B-chunk phys = cb ^ sw(q)
  __shared__ float  Ls[2][64];

  const int t = threadIdx.x;
  const int wid = t >> 6, lane = t & 63;
  const int quad = lane >> 4, l15 = lane & 15;
  const int qt_blk = 15 - blockIdx.x;  // heavy blocks first
  const int h = blockIdx.y, b = blockIdx.z;
  const int kv = h >> 2;
  const int t0 = qt_blk * 128;
  const int r0 = t0 + wid * 64;

  const __bf16* Qb = Q + ((long)(b * NH + h)) * S_LEN * HD;
  const __bf16* Kb = K + ((long)(b * NKV + kv)) * S_LEN * HD;
  const __bf16* Vb = Vt + ((long)(b * NKV + kv)) * HD * S_LEN;
  const float M = 11.3137085f * fabsf(gain[h]);  // score bound

  // Q B-fragments (lane = q-col l15, k = d = c*32 + quad*8 + j)
  bf16x8 qf[4][4];
#pragma unroll
  for (int qt = 0; qt < 4; ++qt)
#pragma unroll
    for (int c = 0; c < 4; ++c)
      qf[qt][c] = *(const bf16x8*)(Qb + (long)(r0 + qt * 16 + l15) * HD + c * 32 + quad * 8);

  f32x4 zero = {0.f, 0.f, 0.f, 0.f};
  f32x4 acc[4][8];
#pragma unroll
  for (int mt = 0; mt < 4; ++mt)
#pragma unroll
    for (int d = 0; d < 8; ++d) acc[mt][d] = zero;
  float lac[4] = {0.f, 0.f, 0.f, 0.f};

  // staging source offsets (4 K-calls + 4 V-calls per thread per tile)
  int ksrc[4], vsrc[4];
#pragma unroll
  for (int j = 0; j < 4; ++j) {
    int kr = j * 8 + (t >> 4);                       // key-row 0..31
    ksrc[j] = kr * HD + (((t & 15) ^ (kr & 15)) << 3);
    int vd = j * 32 + (t >> 2);                      // d-row 0..127
    vsrc[j] = vd * S_LEN + (((t & 3) ^ (vd & 3)) << 3);
  }

  const int kstart = (t0 >= WIN) ? (t0 - WIN) : 0;
  const int ntiles = (t0 + 128 - kstart) >> 5;

  // prologue: stage buf0
#pragma unroll
  for (int j = 0; j < 4; ++j) {
    async_load16(Kb + (long)kstart * HD + ksrc[j], (char*)Ks[0] + j * 2048 + wid * 1024);
    async_load16(Vb + kstart + vsrc[j], (char*)Vs[0] + j * 2048 + wid * 1024);
  }

  for (int it = 0; it < ntiles; ++it) {
    const int kt = kstart + it * 32;
    __syncthreads();  // buf it&1 ready; buf (it+1)&1 free
    if (it + 1 < ntiles) {
      const int kn = kt + 32;
      const int nb = (it + 1) & 1;
#pragma unroll
      for (int j = 0; j < 4; ++j) {
        async_load16(Kb + (long)kn * HD + ksrc[j], (char*)Ks[nb] + j * 2048 + wid * 1024);
        async_load16(Vb + kn + vsrc[j], (char*)Vs[nb] + j * 2048 + wid * 1024);
      }
    }
    if (kt <= r0 + 63 && kt + 31 >= r0 - (WIN - 1)) {
      const __bf16* ksb = Ks[it & 1];
      const __bf16* vsb = Vs[it & 1];
      // S^T = K·Q^T : D[m=key][n=q]; lane: q = l15, keys = quad*4 + r (consecutive!)
#pragma unroll
      for (int kti = 0; kti < 2; ++kti) {
        bf16x8 kf[4];
#pragma unroll
        for (int c = 0; c < 4; ++c)
          kf[c] = *(const bf16x8*)(ksb + (kti * 16 + l15) * 128 +
                                   ((((c << 2) + quad) ^ l15) << 3));
#pragma unroll
        for (int qt = 0; qt < 4; ++qt) {
          f32x4 sc = zero;
#pragma unroll
          for (int c = 0; c < 4; ++c)
            sc = __builtin_amdgcn_mfma_f32_16x16x32_bf16(kf[c], qf[qt][c], sc, 0, 0, 0);
          const int q = qt * 16 + l15;
          const int qg = r0 + q;
          const int kbase = kt + kti * 16 + quad * 4;
          bf16x4 pv;
#pragma unroll
          for (int r = 0; r < 4; ++r) {
            int key = kbase + r;
            float p = (key <= qg && key >= qg - (WIN - 1)) ? __expf(sc[r] - M) : 0.f;
            lac[qt] += p;
            pv[r] = (__bf16)p;
          }
          const int sw = (q + (q >> 3)) & 7;
          const int cb = kti * 4 + quad;
          *(bf16x4*)(&Ps[wid][q * 32 + ((cb ^ sw) << 2)]) = pv;  // b64 write
        }
      }
      // PV: pf = A-frag of P (same-wave LDS round trip, in-order)
      bf16x8 pf[4];
#pragma unroll
      for (int mt = 0; mt < 4; ++mt) {
        const int q = mt * 16 + l15;
        const int sw = (q + (q >> 3)) & 7;
        U8 u;
        u.h[0] = *(const bf16x4*)(&Ps[wid][q * 32 + (((2 * quad) ^ sw) << 2)]);
        u.h[1] = *(const bf16x4*)(&Ps[wid][q * 32 + (((2 * quad + 1) ^ sw) << 2)]);
        pf[mt] = u.v;
      }
#pragma unroll
      for (int dt = 0; dt < 8; ++dt) {
        bf16x8 vf = *(const bf16x8*)(vsb + (dt * 16 + l15) * 32 +
                                     ((quad ^ (l15 & 3)) << 3));
#pragma unroll
        for (int mt = 0; mt < 4; ++mt)
          acc[mt][dt] = __builtin_amdgcn_mfma_f32_16x16x32_bf16(pf[mt], vf, acc[mt][dt], 0, 0, 0);
      }
    }
  }

  // epilogue: reduce l across quads (lanes sharing q), broadcast via LDS
#pragma unroll
  for (int qt = 0; qt < 4; ++qt) {
    float s = lac[qt];
    s += __shfl_xor(s, 16, 64);
    s += __shfl_xor(s, 32, 64);
    if (quad == 0) Ls[wid][qt * 16 + l15] = s;
  }
  __bf16* Yb = Y + ((long)b * S_LEN) * DIM + h * HD;
#pragma unroll
  for (int mt = 0; mt < 4; ++mt)
#pragma unroll
    for (int r = 0; r < 4; ++r) {
      float il = 1.f / Ls[wid][mt * 16 + quad * 4 + r];
      const long row = r0 + mt * 16 + quad * 4 + r;
#pragma unroll
      for (int dt = 0; dt < 8; ++dt)
        Yb[row * DIM + dt * 16 + l15] = (__bf16)(acc[mt][dt][r] * il);
    }
}

// ---------------- launch ----------------
extern "C" void kernel_launch(void* const* d_in, const int* in_sizes, int n_in,
                              void* d_out, int out_size, void* d_ws, size_t ws_size,
                              hipStream_t stream) {
  (void)in_sizes; (void)n_in; (void)out_size; (void)ws_size;
  const float* x  = (const float*)d_in[0];
  const float* Wq = (const float*)d_in[1];
  const float* Wk = (const float*)d_in[2];
  const float* Wv = (const float*)d_in[3];
  const float* Wo = (const float*)d_in[4];
  const float* qg = (const float*)d_in[5];
  float* out = (float*)d_out;

  char* ws = (char*)d_ws;
  size_t off = 0;
  auto alloc = [&](size_t bytes) -> void* {
    void* p = ws + off;
    off += (bytes + 255) & ~(size_t)255;
    return p;
  };
  __bf16* xb   = (__bf16*)alloc(8388608ull * 2);      // x bf16; reused as yb
  __bf16* wqkv = (__bf16*)alloc(3072ull * 2048 * 2);  // permuted q/k weight rows
  __bf16* wob  = (__bf16*)alloc(2048ull * 2048 * 2);
  __bf16* qo   = (__bf16*)alloc((size_t)BATCH * NH * S_LEN * HD * 2);
  __bf16* ko   = (__bf16*)alloc((size_t)BATCH * NKV * S_LEN * HD * 2);
  __bf16* vt   = (__bf16*)alloc((size_t)BATCH * NKV * HD * S_LEN * 2);
  float*  cosT = (float*)alloc(2048ull * 64 * 4);
  float*  sinT = (float*)alloc(2048ull * 64 * 4);
  __bf16* yb   = xb;

  preprocess_kernel<<<18944, 256, 0, stream>>>(x, Wq, Wk, Wv, Wo, xb, wqkv, wob,
                                               cosT, sinT);
  gemm_qkv<<<dim3(32, 24), 256, 0, stream>>>(xb, wqkv, qg, cosT, sinT, qo, ko, vt);
  attn_kernel<<<dim3(16, 16, 2), 128, 0, stream>>>(qo, ko, vt, qg, yb);
  gemm_bt<<<dim3(32, 16), 256, 0, stream>>>(yb, wob, out, 4096, 2048, 2048);
}

// Round 5
// 272.334 us; speedup vs baseline: 1.1784x; 1.1784x over previous
//
#include <hip/hip_runtime.h>

#define S_LEN 2048
#define DIM   2048
#define NH    16
#define NKV   4
#define HD    128
#define WIN   512
#define BATCH 2

typedef __bf16 bf16x8 __attribute__((ext_vector_type(8)));
typedef __bf16 bf16x4 __attribute__((ext_vector_type(4)));
typedef float  f32x4  __attribute__((ext_vector_type(4)));

union U8 { bf16x8 v; bf16x4 h[2]; };

__device__ inline void async_load16(const void* g, void* l) {
  __builtin_amdgcn_global_load_lds(
      (const __attribute__((address_space(1))) unsigned int*)g,
      (__attribute__((address_space(3))) unsigned int*)l, 16, 0, 0);
}

// ------------- merged preprocess: x cast | weight cast+perm | rope tables ----
__global__ __launch_bounds__(256) void preprocess_kernel(
    const float* __restrict__ x,
    const float* __restrict__ Wq, const float* __restrict__ Wk,
    const float* __restrict__ Wv, const float* __restrict__ Wo,
    __bf16* __restrict__ xb, __bf16* __restrict__ wqkv, __bf16* __restrict__ wob,
    float* __restrict__ cosT, float* __restrict__ sinT) {
  const int blk = blockIdx.x, tid = threadIdx.x;
  if (blk < 8192) {
    int i = blk * 256 + tid;  // x: 2097152 float4
    float4 v = ((const float4*)x)[i];
    bf16x4 o;
    o[0] = (__bf16)v.x; o[1] = (__bf16)v.y; o[2] = (__bf16)v.z; o[3] = (__bf16)v.w;
    ((bf16x4*)xb)[i] = o;
  } else if (blk < 18432) {
    int i = (blk - 8192) * 256 + tid;  // weights: 5120 rows x 512 float4
    int orow = i >> 9, c = i & 511;
    const float* src;
    __bf16* dst;
    long soff;
    if (orow < 2048) {
      int n = orow & 127;
      int sr = (orow & ~127) + ((n >> 5) << 4) + (n & 15) + (((n >> 4) & 1) << 6);
      src = Wq; soff = (long)sr * 512 + c; dst = wqkv + (long)orow * 2048;
    } else if (orow < 2560) {
      int lr = orow - 2048, n = lr & 127;
      int sr = (lr & ~127) + ((n >> 5) << 4) + (n & 15) + (((n >> 4) & 1) << 6);
      src = Wk; soff = (long)sr * 512 + c; dst = wqkv + (long)orow * 2048;
    } else if (orow < 3072) {
      src = Wv; soff = (long)(orow - 2560) * 512 + c; dst = wqkv + (long)orow * 2048;
    } else {
      src = Wo; soff = (long)(orow - 3072) * 512 + c; dst = wob + (long)(orow - 3072) * 2048;
    }
    float4 v = ((const float4*)src)[soff];
    bf16x4 o;
    o[0] = (__bf16)v.x; o[1] = (__bf16)v.y; o[2] = (__bf16)v.z; o[3] = (__bf16)v.w;
    ((bf16x4*)dst)[c] = o;
  } else {
    int idx = (blk - 18432) * 256 + tid;  // rope: 131072
    int s = idx >> 6, d = idx & 63;
    float f = (float)s * powf(10000.f, -(float)d * (1.f / 64.f));
    float sn, cs;
    sincosf(f, &sn, &cs);
    cosT[idx] = cs;
    sinT[idx] = sn;
  }
}

// -------- O-projection GEMM: r3-proven m97 structure (2-barrier, 1 buf) -----
__global__ __launch_bounds__(256) void gemm_bt(
    const __bf16* __restrict__ A, const __bf16* __restrict__ Bt,
    float* __restrict__ C, int M, int N, int K) {
  __shared__ __bf16 As[128 * 32];
  __shared__ __bf16 Bs[128 * 32];
  const int t = threadIdx.x;
  const int wid = t >> 6, lane = t & 63;
  const int quad = lane >> 4, l15 = lane & 15;
  const long m0 = (long)blockIdx.x * 128, n0 = (long)blockIdx.y * 128;
  const int wm = (wid >> 1) * 64, wn = (wid & 1) * 64;

  const __bf16* ga = A + (m0 + (t >> 2)) * (long)K + (t & 3) * 8;
  const __bf16* gb = Bt + (n0 + (t >> 2)) * (long)K + (t & 3) * 8;
  char* lA = (char*)As + wid * 1024;
  char* lB = (char*)Bs + wid * 1024;
  const long rstride = 64L * K;

  f32x4 zero = {0.f, 0.f, 0.f, 0.f};
  f32x4 acc[4][4];
#pragma unroll
  for (int i = 0; i < 4; ++i)
#pragma unroll
    for (int j = 0; j < 4; ++j) acc[i][j] = zero;

  for (int k0 = 0; k0 < K; k0 += 32) {
    async_load16(ga + k0, lA);
    async_load16(ga + k0 + rstride, lA + 4096);
    async_load16(gb + k0, lB);
    async_load16(gb + k0 + rstride, lB + 4096);
    __syncthreads();
    bf16x8 af[4], bfr[4];
#pragma unroll
    for (int i = 0; i < 4; ++i) {
      af[i] = *(const bf16x8*)(As + (wm + i * 16 + l15) * 32 + quad * 8);
      bfr[i] = *(const bf16x8*)(Bs + (wn + i * 16 + l15) * 32 + quad * 8);
    }
#pragma unroll
    for (int i = 0; i < 4; ++i)
#pragma unroll
      for (int j = 0; j < 4; ++j)
        acc[i][j] = __builtin_amdgcn_mfma_f32_16x16x32_bf16(af[i], bfr[j], acc[i][j], 0, 0, 0);
    __syncthreads();
  }

#pragma unroll
  for (int i = 0; i < 4; ++i)
#pragma unroll
    for (int j = 0; j < 4; ++j)
#pragma unroll
      for (int r = 0; r < 4; ++r)
        C[(m0 + wm + i * 16 + quad * 4 + r) * (long)N + n0 + wn + j * 16 + l15] = acc[i][j][r];
}

// -------- QKV GEMM (r3 structure) + fused RMSNorm/RoPE/gain/V-transpose -----
__global__ __launch_bounds__(256) void gemm_qkv(
    const __bf16* __restrict__ A, const __bf16* __restrict__ Bt,
    const float* __restrict__ gain,
    const float* __restrict__ cosT, const float* __restrict__ sinT,
    __bf16* __restrict__ Qo, __bf16* __restrict__ Ko, __bf16* __restrict__ Vt) {
  __shared__ __bf16 As[128 * 32];
  __shared__ __bf16 Bs[128 * 32];
  const int K = 2048;
  const int t = threadIdx.x;
  const int wid = t >> 6, lane = t & 63;
  const int quad = lane >> 4, l15 = lane & 15;
  const long m0 = (long)blockIdx.x * 128, n0 = (long)blockIdx.y * 128;
  const int wm = (wid >> 1) * 64, wn = (wid & 1) * 64;

  const __bf16* ga = A + (m0 + (t >> 2)) * (long)K + (t & 3) * 8;
  const __bf16* gb = Bt + (n0 + (t >> 2)) * (long)K + (t & 3) * 8;
  char* lA = (char*)As + wid * 1024;
  char* lB = (char*)Bs + wid * 1024;
  const long rstride = 64L * K;

  f32x4 zero = {0.f, 0.f, 0.f, 0.f};
  f32x4 acc[4][4];
#pragma unroll
  for (int i = 0; i < 4; ++i)
#pragma unroll
    for (int j = 0; j < 4; ++j) acc[i][j] = zero;

  for (int k0 = 0; k0 < K; k0 += 32) {
    async_load16(ga + k0, lA);
    async_load16(ga + k0 + rstride, lA + 4096);
    async_load16(gb + k0, lB);
    async_load16(gb + k0 + rstride, lB + 4096);
    __syncthreads();
    bf16x8 af[4], bfr[4];
#pragma unroll
    for (int i = 0; i < 4; ++i) {
      af[i] = *(const bf16x8*)(As + (wm + i * 16 + l15) * 32 + quad * 8);
      bfr[i] = *(const bf16x8*)(Bs + (wn + i * 16 + l15) * 32 + quad * 8);
    }
#pragma unroll
    for (int i = 0; i < 4; ++i)
#pragma unroll
      for (int j = 0; j < 4; ++j)
        acc[i][j] = __builtin_amdgcn_mfma_f32_16x16x32_bf16(af[i], bfr[j], acc[i][j], 0, 0, 0);
    __syncthreads();
  }

  const int by = blockIdx.y;
  const int srow0 = (int)(m0 & 2047);
  const int bb = (int)(m0 >> 11);

  if (by >= 20) {
    const int kvh = by - 20;
    __bf16* Vb = Vt + ((long)(bb * NKV + kvh)) * HD * S_LEN;
#pragma unroll
    for (int i = 0; i < 4; ++i)
#pragma unroll
      for (int j = 0; j < 4; ++j) {
        int d = wn + j * 16 + l15;
        int s0 = srow0 + wm + i * 16 + quad * 4;
        bf16x4 o;
#pragma unroll
        for (int r = 0; r < 4; ++r) o[r] = (__bf16)acc[i][j][r];
        *(bf16x4*)(Vb + (long)d * S_LEN + s0) = o;
      }
  } else {
    float* sums = (float*)As;
#pragma unroll
    for (int i = 0; i < 4; ++i)
#pragma unroll
      for (int r = 0; r < 4; ++r) {
        float t2 = acc[i][0][r] * acc[i][0][r] + acc[i][1][r] * acc[i][1][r] +
                   acc[i][2][r] * acc[i][2][r] + acc[i][3][r] * acc[i][3][r];
#pragma unroll
        for (int off = 1; off < 16; off <<= 1) t2 += __shfl_xor(t2, off, 64);
        if (l15 == 0) sums[(wm + i * 16 + quad * 4 + r) * 2 + (wn >> 6)] = t2;
      }
    __syncthreads();

    float g;
    __bf16* base;
    if (by < 16) {
      g = gain[by] * 0.08838834764831845f;
      base = Qo + ((long)(bb * NH + by)) * S_LEN * HD;
    } else {
      g = 1.f;
      base = Ko + ((long)(bb * NKV + (by - 16))) * S_LEN * HD;
    }
#pragma unroll
    for (int i = 0; i < 4; ++i)
#pragma unroll
      for (int r = 0; r < 4; ++r) {
        int lrow = wm + i * 16 + quad * 4 + r;
        int srow = srow0 + lrow;
        float rs = rsqrtf((sums[lrow * 2] + sums[lrow * 2 + 1]) * (1.f / 128.f) +
                          1.1920928955078125e-07f);
#pragma unroll
        for (int a = 0; a < 2; ++a) {
          int dlow = (wn >> 1) + a * 16 + l15;
          float cv = cosT[srow * 64 + dlow];
          float sv = sinT[srow * 64 + dlow];
          float x1 = acc[i][2 * a][r] * rs;
          float x2 = acc[i][2 * a + 1][r] * rs;
          base[(long)srow * HD + wn + (2 * a) * 16 + l15] = (__bf16)((x1 * cv + x2 * sv) * g);
          base[(long)srow * HD + wn + (2 * a + 1) * 16 + l15] = (__bf16)((-x1 * sv + x2 * cv) * g);
        }
      }
  }
}

// --------- attention: S^T trick, 64 q-rows/wave, TK=64, 2-barrier 1-buf -----
// block = 2 waves x 64 q-rows = 128-row span; loads issued BEFORE barrier
// (m97 order -> no false vmcnt dependency on ds_read).
__global__ __launch_bounds__(128, 1) void attn_kernel(
    const __bf16* __restrict__ Q,   // [B][NH][S][HD] (perm d, pre-scaled)
    const __bf16* __restrict__ K,   // [B][NKV][S][HD] (perm d)
    const __bf16* __restrict__ Vt,  // [B][NKV][HD][S] (true d)
    const float* __restrict__ gain,
    __bf16* __restrict__ Y) {       // [B][S][NH*HD]
  __shared__ __bf16 Ks[64 * 128];  // [key][d], 16B-chunk phys = logical ^ (key&15)
  __shared__ __bf16 Vs[128 * 64];  // [d][key], 8-chunk rows, phys = logical ^ (d&7)
  __shared__ __bf16 Ps[2][64 * 64];  // per-wave P [q][key], 8B-chunk phys = cb ^ (q&15)
  __shared__ float  Ls[2][64];

  const int t = threadIdx.x;
  const int wid = t >> 6, lane = t & 63;
  const int quad = lane >> 4, l15 = lane & 15;
  const int qt_blk = 15 - blockIdx.x;  // heavy blocks first
  const int h = blockIdx.y, b = blockIdx.z;
  const int kv = h >> 2;
  const int t0 = qt_blk * 128;
  const int r0 = t0 + wid * 64;

  const __bf16* Qb = Q + ((long)(b * NH + h)) * S_LEN * HD;
  const __bf16* Kb = K + ((long)(b * NKV + kv)) * S_LEN * HD;
  const __bf16* Vb = Vt + ((long)(b * NKV + kv)) * HD * S_LEN;
  const float M = 11.3137085f * fabsf(gain[h]);  // score bound

  // Q B-fragments: qf[qt][c] = Q[r0+qt*16+l15][c*32+quad*8+j]
  bf16x8 qf[4][4];
#pragma unroll
  for (int qt = 0; qt < 4; ++qt)
#pragma unroll
    for (int c = 0; c < 4; ++c)
      qf[qt][c] = *(const bf16x8*)(Qb + (long)(r0 + qt * 16 + l15) * HD + c * 32 + quad * 8);

  f32x4 zero = {0.f, 0.f, 0.f, 0.f};
  f32x4 acc[4][8];
#pragma unroll
  for (int mt = 0; mt < 4; ++mt)
#pragma unroll
    for (int d = 0; d < 8; ++d) acc[mt][d] = zero;
  float lac[4] = {0.f, 0.f, 0.f, 0.f};

  // staging: 8 K-rounds + 8 V-rounds per tile, 2 KB each (128 thr x 16 B)
  int ksrc[8], vsrc[8];
#pragma unroll
  for (int j = 0; j < 8; ++j) {
    int kr = j * 8 + (t >> 4);        // key-row 0..63
    ksrc[j] = kr * HD + (((t & 15) ^ (kr & 15)) << 3);
    int vd = j * 16 + (t >> 3);       // d-row 0..127
    vsrc[j] = vd * S_LEN + (((t & 7) ^ (vd & 7)) << 3);
  }

  const int kstart = (t0 >= WIN) ? (t0 - WIN) : 0;
  const int ntiles = (t0 + 128 - kstart) >> 6;

  for (int it = 0; it < ntiles; ++it) {
    const int kt = kstart + it * 64;
#pragma unroll
    for (int j = 0; j < 8; ++j) {
      async_load16(Kb + (long)kt * HD + ksrc[j], (char*)Ks + j * 2048 + t * 16);
      async_load16(Vb + kt + vsrc[j], (char*)Vs + j * 2048 + t * 16);
    }
    __syncthreads();  // drain staging

    if (kt <= r0 + 63 && kt + 63 >= r0 - (WIN - 1)) {
      // S^T = K·Q^T: lane q = l15, keys = quad*4+r (consecutive -> packed write)
#pragma unroll
      for (int kti = 0; kti < 4; ++kti) {
        bf16x8 kf[4];
#pragma unroll
        for (int c = 0; c < 4; ++c)
          kf[c] = *(const bf16x8*)(Ks + (kti * 16 + l15) * 128 +
                                   ((((c << 2) + quad) ^ l15) << 3));
#pragma unroll
        for (int qt = 0; qt < 4; ++qt) {
          f32x4 sc = zero;
#pragma unroll
          for (int c = 0; c < 4; ++c)
            sc = __builtin_amdgcn_mfma_f32_16x16x32_bf16(kf[c], qf[qt][c], sc, 0, 0, 0);
          const int q = qt * 16 + l15;
          const int qg = r0 + q;
          const int kbase = kt + kti * 16 + quad * 4;
          bf16x4 pv;
#pragma unroll
          for (int r = 0; r < 4; ++r) {
            int key = kbase + r;
            float p = (key <= qg && key >= qg - (WIN - 1)) ? __expf(sc[r] - M) : 0.f;
            lac[qt] += p;
            pv[r] = (__bf16)p;
          }
          const int cb = kti * 4 + quad;  // 8B-chunk index 0..15
          *(bf16x4*)(&Ps[wid][q * 64 + ((cb ^ l15) << 2)]) = pv;
        }
      }
      // P A-fragments + PV
      bf16x8 pf[4][2];
#pragma unroll
      for (int mt = 0; mt < 4; ++mt)
#pragma unroll
        for (int kc = 0; kc < 2; ++kc) {
          const int q = mt * 16 + l15;
          U8 u;
          u.h[0] = *(const bf16x4*)(&Ps[wid][q * 64 + (((kc * 8 + quad * 2) ^ l15) << 2)]);
          u.h[1] = *(const bf16x4*)(&Ps[wid][q * 64 + (((kc * 8 + quad * 2 + 1) ^ l15) << 2)]);
          pf[mt][kc] = u.v;
        }
#pragma unroll
      for (int dt = 0; dt < 8; ++dt)
#pragma unroll
        for (int kc = 0; kc < 2; ++kc) {
          bf16x8 vf = *(const bf16x8*)(Vs + (dt * 16 + l15) * 64 +
                                       ((((kc << 2) + quad) ^ (l15 & 7)) << 3));
#pragma unroll
          for (int mt = 0; mt < 4; ++mt)
            acc[mt][dt] = __builtin_amdgcn_mfma_f32_16x16x32_bf16(pf[mt][kc], vf, acc[mt][dt], 0, 0, 0);
        }
    }
    __syncthreads();  // protect single buffer before next staging
  }

  // epilogue: reduce l across quads, broadcast via LDS, normalize, store
#pragma unroll
  for (int qt = 0; qt < 4; ++qt) {
    float s = lac[qt];
    s += __shfl_xor(s, 16, 64);
    s += __shfl_xor(s, 32, 64);
    if (quad == 0) Ls[wid][qt * 16 + l15] = s;
  }
  __bf16* Yb = Y + ((long)b * S_LEN) * DIM + h * HD;
#pragma unroll
  for (int mt = 0; mt < 4; ++mt)
#pragma unroll
    for (int r = 0; r < 4; ++r) {
      float il = 1.f / Ls[wid][mt * 16 + quad * 4 + r];
      const long row = r0 + mt * 16 + quad * 4 + r;
#pragma unroll
      for (int dt = 0; dt < 8; ++dt)
        Yb[row * DIM + dt * 16 + l15] = (__bf16)(acc[mt][dt][r] * il);
    }
}

// ---------------- launch ----------------
extern "C" void kernel_launch(void* const* d_in, const int* in_sizes, int n_in,
                              void* d_out, int out_size, void* d_ws, size_t ws_size,
                              hipStream_t stream) {
  (void)in_sizes; (void)n_in; (void)out_size; (void)ws_size;
  const float* x  = (const float*)d_in[0];
  const float* Wq = (const float*)d_in[1];
  const float* Wk = (const float*)d_in[2];
  const float* Wv = (const float*)d_in[3];
  const float* Wo = (const float*)d_in[4];
  const float* qg = (const float*)d_in[5];
  float* out = (float*)d_out;

  char* ws = (char*)d_ws;
  size_t off = 0;
  auto alloc = [&](size_t bytes) -> void* {
    void* p = ws + off;
    off += (bytes + 255) & ~(size_t)255;
    return p;
  };
  __bf16* xb   = (__bf16*)alloc(8388608ull * 2);      // x bf16; reused as yb
  __bf16* wqkv = (__bf16*)alloc(3072ull * 2048 * 2);  // permuted q/k weight rows
  __bf16* wob  = (__bf16*)alloc(2048ull * 2048 * 2);
  __bf16* qo   = (__bf16*)alloc((size_t)BATCH * NH * S_LEN * HD * 2);
  __bf16* ko   = (__bf16*)alloc((size_t)BATCH * NKV * S_LEN * HD * 2);
  __bf16* vt   = (__bf16*)alloc((size_t)BATCH * NKV * HD * S_LEN * 2);
  float*  cosT = (float*)alloc(2048ull * 64 * 4);
  float*  sinT = (float*)alloc(2048ull * 64 * 4);
  __bf16* yb   = xb;

  preprocess_kernel<<<18944, 256, 0, stream>>>(x, Wq, Wk, Wv, Wo, xb, wqkv, wob,
                                               cosT, sinT);
  gemm_qkv<<<dim3(32, 24), 256, 0, stream>>>(xb, wqkv, qg, cosT, sinT, qo, ko, vt);
  attn_kernel<<<dim3(16, 16, 2), 128, 0, stream>>>(qo, ko, vt, qg, yb);
  gemm_bt<<<dim3(32, 16), 256, 0, stream>>>(yb, wob, out, 4096, 2048, 2048);
}

// Round 6
// 262.104 us; speedup vs baseline: 1.2244x; 1.0390x over previous
//
#include <hip/hip_runtime.h>

#define S_LEN 2048
#define DIM   2048
#define NH    16
#define NKV   4
#define HD    128
#define WIN   512
#define BATCH 2

typedef __bf16 bf16x8 __attribute__((ext_vector_type(8)));
typedef __bf16 bf16x4 __attribute__((ext_vector_type(4)));
typedef float  f32x4  __attribute__((ext_vector_type(4)));

union U8 { bf16x8 v; bf16x4 h[2]; };

__device__ inline void async_load16(const void* g, void* l) {
  __builtin_amdgcn_global_load_lds(
      (const __attribute__((address_space(1))) unsigned int*)g,
      (__attribute__((address_space(3))) unsigned int*)l, 16, 0, 0);
}

// ------------- merged preprocess: x cast | weight cast+perm | rope tables ----
__global__ __launch_bounds__(256) void preprocess_kernel(
    const float* __restrict__ x,
    const float* __restrict__ Wq, const float* __restrict__ Wk,
    const float* __restrict__ Wv, const float* __restrict__ Wo,
    __bf16* __restrict__ xb, __bf16* __restrict__ wqkv, __bf16* __restrict__ wob,
    float* __restrict__ cosT, float* __restrict__ sinT) {
  const int blk = blockIdx.x, tid = threadIdx.x;
  if (blk < 8192) {
    int i = blk * 256 + tid;  // x: 2097152 float4
    float4 v = ((const float4*)x)[i];
    bf16x4 o;
    o[0] = (__bf16)v.x; o[1] = (__bf16)v.y; o[2] = (__bf16)v.z; o[3] = (__bf16)v.w;
    ((bf16x4*)xb)[i] = o;
  } else if (blk < 18432) {
    int i = (blk - 8192) * 256 + tid;  // weights: 5120 rows x 512 float4
    int orow = i >> 9, c = i & 511;
    const float* src;
    __bf16* dst;
    long soff;
    if (orow < 2048) {
      int n = orow & 127;
      int sr = (orow & ~127) + ((n >> 5) << 4) + (n & 15) + (((n >> 4) & 1) << 6);
      src = Wq; soff = (long)sr * 512 + c; dst = wqkv + (long)orow * 2048;
    } else if (orow < 2560) {
      int lr = orow - 2048, n = lr & 127;
      int sr = (lr & ~127) + ((n >> 5) << 4) + (n & 15) + (((n >> 4) & 1) << 6);
      src = Wk; soff = (long)sr * 512 + c; dst = wqkv + (long)orow * 2048;
    } else if (orow < 3072) {
      src = Wv; soff = (long)(orow - 2560) * 512 + c; dst = wqkv + (long)orow * 2048;
    } else {
      src = Wo; soff = (long)(orow - 3072) * 512 + c; dst = wob + (long)(orow - 3072) * 2048;
    }
    float4 v = ((const float4*)src)[soff];
    bf16x4 o;
    o[0] = (__bf16)v.x; o[1] = (__bf16)v.y; o[2] = (__bf16)v.z; o[3] = (__bf16)v.w;
    ((bf16x4*)dst)[c] = o;
  } else {
    int idx = (blk - 18432) * 256 + tid;  // rope: 131072
    int s = idx >> 6, d = idx & 63;
    float f = (float)s * powf(10000.f, -(float)d * (1.f / 64.f));
    float sn, cs;
    sincosf(f, &sn, &cs);
    cosT[idx] = cs;
    sinT[idx] = sn;
  }
}

// -------- O-projection GEMM: m97 structure (2-barrier, 1 buf) -----
__global__ __launch_bounds__(256) void gemm_bt(
    const __bf16* __restrict__ A, const __bf16* __restrict__ Bt,
    float* __restrict__ C, int M, int N, int K) {
  __shared__ __bf16 As[128 * 32];
  __shared__ __bf16 Bs[128 * 32];
  const int t = threadIdx.x;
  const int wid = t >> 6, lane = t & 63;
  const int quad = lane >> 4, l15 = lane & 15;
  const long m0 = (long)blockIdx.x * 128, n0 = (long)blockIdx.y * 128;
  const int wm = (wid >> 1) * 64, wn = (wid & 1) * 64;

  const __bf16* ga = A + (m0 + (t >> 2)) * (long)K + (t & 3) * 8;
  const __bf16* gb = Bt + (n0 + (t >> 2)) * (long)K + (t & 3) * 8;
  char* lA = (char*)As + wid * 1024;
  char* lB = (char*)Bs + wid * 1024;
  const long rstride = 64L * K;

  f32x4 zero = {0.f, 0.f, 0.f, 0.f};
  f32x4 acc[4][4];
#pragma unroll
  for (int i = 0; i < 4; ++i)
#pragma unroll
    for (int j = 0; j < 4; ++j) acc[i][j] = zero;

  for (int k0 = 0; k0 < K; k0 += 32) {
    async_load16(ga + k0, lA);
    async_load16(ga + k0 + rstride, lA + 4096);
    async_load16(gb + k0, lB);
    async_load16(gb + k0 + rstride, lB + 4096);
    __syncthreads();
    bf16x8 af[4], bfr[4];
#pragma unroll
    for (int i = 0; i < 4; ++i) {
      af[i] = *(const bf16x8*)(As + (wm + i * 16 + l15) * 32 + quad * 8);
      bfr[i] = *(const bf16x8*)(Bs + (wn + i * 16 + l15) * 32 + quad * 8);
    }
#pragma unroll
    for (int i = 0; i < 4; ++i)
#pragma unroll
      for (int j = 0; j < 4; ++j)
        acc[i][j] = __builtin_amdgcn_mfma_f32_16x16x32_bf16(af[i], bfr[j], acc[i][j], 0, 0, 0);
    __syncthreads();
  }

#pragma unroll
  for (int i = 0; i < 4; ++i)
#pragma unroll
    for (int j = 0; j < 4; ++j)
#pragma unroll
      for (int r = 0; r < 4; ++r)
        C[(m0 + wm + i * 16 + quad * 4 + r) * (long)N + n0 + wn + j * 16 + l15] = acc[i][j][r];
}

// -------- QKV GEMM (m97 structure) + fused RMSNorm/RoPE/gain/V-transpose ----
__global__ __launch_bounds__(256) void gemm_qkv(
    const __bf16* __restrict__ A, const __bf16* __restrict__ Bt,
    const float* __restrict__ gain,
    const float* __restrict__ cosT, const float* __restrict__ sinT,
    __bf16* __restrict__ Qo, __bf16* __restrict__ Ko, __bf16* __restrict__ Vt) {
  __shared__ __bf16 As[128 * 32];
  __shared__ __bf16 Bs[128 * 32];
  const int K = 2048;
  const int t = threadIdx.x;
  const int wid = t >> 6, lane = t & 63;
  const int quad = lane >> 4, l15 = lane & 15;
  const long m0 = (long)blockIdx.x * 128, n0 = (long)blockIdx.y * 128;
  const int wm = (wid >> 1) * 64, wn = (wid & 1) * 64;

  const __bf16* ga = A + (m0 + (t >> 2)) * (long)K + (t & 3) * 8;
  const __bf16* gb = Bt + (n0 + (t >> 2)) * (long)K + (t & 3) * 8;
  char* lA = (char*)As + wid * 1024;
  char* lB = (char*)Bs + wid * 1024;
  const long rstride = 64L * K;

  f32x4 zero = {0.f, 0.f, 0.f, 0.f};
  f32x4 acc[4][4];
#pragma unroll
  for (int i = 0; i < 4; ++i)
#pragma unroll
    for (int j = 0; j < 4; ++j) acc[i][j] = zero;

  for (int k0 = 0; k0 < K; k0 += 32) {
    async_load16(ga + k0, lA);
    async_load16(ga + k0 + rstride, lA + 4096);
    async_load16(gb + k0, lB);
    async_load16(gb + k0 + rstride, lB + 4096);
    __syncthreads();
    bf16x8 af[4], bfr[4];
#pragma unroll
    for (int i = 0; i < 4; ++i) {
      af[i] = *(const bf16x8*)(As + (wm + i * 16 + l15) * 32 + quad * 8);
      bfr[i] = *(const bf16x8*)(Bs + (wn + i * 16 + l15) * 32 + quad * 8);
    }
#pragma unroll
    for (int i = 0; i < 4; ++i)
#pragma unroll
      for (int j = 0; j < 4; ++j)
        acc[i][j] = __builtin_amdgcn_mfma_f32_16x16x32_bf16(af[i], bfr[j], acc[i][j], 0, 0, 0);
    __syncthreads();
  }

  const int by = blockIdx.y;
  const int srow0 = (int)(m0 & 2047);
  const int bb = (int)(m0 >> 11);

  if (by >= 20) {
    const int kvh = by - 20;
    __bf16* Vb = Vt + ((long)(bb * NKV + kvh)) * HD * S_LEN;
#pragma unroll
    for (int i = 0; i < 4; ++i)
#pragma unroll
      for (int j = 0; j < 4; ++j) {
        int d = wn + j * 16 + l15;
        int s0 = srow0 + wm + i * 16 + quad * 4;
        bf16x4 o;
#pragma unroll
        for (int r = 0; r < 4; ++r) o[r] = (__bf16)acc[i][j][r];
        *(bf16x4*)(Vb + (long)d * S_LEN + s0) = o;
      }
  } else {
    float* sums = (float*)As;
#pragma unroll
    for (int i = 0; i < 4; ++i)
#pragma unroll
      for (int r = 0; r < 4; ++r) {
        float t2 = acc[i][0][r] * acc[i][0][r] + acc[i][1][r] * acc[i][1][r] +
                   acc[i][2][r] * acc[i][2][r] + acc[i][3][r] * acc[i][3][r];
#pragma unroll
        for (int off = 1; off < 16; off <<= 1) t2 += __shfl_xor(t2, off, 64);
        if (l15 == 0) sums[(wm + i * 16 + quad * 4 + r) * 2 + (wn >> 6)] = t2;
      }
    __syncthreads();

    float g;
    __bf16* base;
    if (by < 16) {
      g = gain[by] * 0.08838834764831845f;
      base = Qo + ((long)(bb * NH + by)) * S_LEN * HD;
    } else {
      g = 1.f;
      base = Ko + ((long)(bb * NKV + (by - 16))) * S_LEN * HD;
    }
#pragma unroll
    for (int i = 0; i < 4; ++i)
#pragma unroll
      for (int r = 0; r < 4; ++r) {
        int lrow = wm + i * 16 + quad * 4 + r;
        int srow = srow0 + lrow;
        float rs = rsqrtf((sums[lrow * 2] + sums[lrow * 2 + 1]) * (1.f / 128.f) +
                          1.1920928955078125e-07f);
#pragma unroll
        for (int a = 0; a < 2; ++a) {
          int dlow = (wn >> 1) + a * 16 + l15;
          float cv = cosT[srow * 64 + dlow];
          float sv = sinT[srow * 64 + dlow];
          float x1 = acc[i][2 * a][r] * rs;
          float x2 = acc[i][2 * a + 1][r] * rs;
          base[(long)srow * HD + wn + (2 * a) * 16 + l15] = (__bf16)((x1 * cv + x2 * sv) * g);
          base[(long)srow * HD + wn + (2 * a + 1) * 16 + l15] = (__bf16)((-x1 * sv + x2 * cv) * g);
        }
      }
  }
}

// ---- attention: S^T trick, 4 waves x 16 q-rows, TK=64, high occupancy ----
// grid (32,16,2)=1024 blocks; LDS exactly 40960 B -> 4 blocks/CU (160 KB);
// __launch_bounds__(256,4) caps VGPR at 128 -> 16 waves/CU, 4/SIMD.
__global__ __launch_bounds__(256, 4) void attn_kernel(
    const __bf16* __restrict__ Q,   // [B][NH][S][HD] (perm d, pre-scaled)
    const __bf16* __restrict__ K,   // [B][NKV][S][HD] (perm d)
    const __bf16* __restrict__ Vt,  // [B][NKV][HD][S] (true d)
    const float* __restrict__ gain,
    __bf16* __restrict__ Y) {       // [B][S][NH*HD]
  __shared__ __bf16 Ks[64 * 128];   // [key][d], 16B-chunk phys = logical ^ (key&15)
  __shared__ __bf16 Vs[128 * 64];   // [d][key], 16B-chunk phys = logical ^ (d&7)
  __shared__ __bf16 Ps[4][16 * 64]; // per-wave P [q][key], 8B-chunk phys = cb ^ q

  const int t = threadIdx.x;
  const int wid = t >> 6, lane = t & 63;
  const int quad = lane >> 4, l15 = lane & 15;
  const int qt_blk = 31 - blockIdx.x;  // heavy blocks first
  const int h = blockIdx.y, b = blockIdx.z;
  const int kv = h >> 2;
  const int t0 = qt_blk * 64;
  const int r0 = t0 + wid * 16;

  const __bf16* Qb = Q + ((long)(b * NH + h)) * S_LEN * HD;
  const __bf16* Kb = K + ((long)(b * NKV + kv)) * S_LEN * HD;
  const __bf16* Vb = Vt + ((long)(b * NKV + kv)) * HD * S_LEN;
  const float M = 11.3137085f * fabsf(gain[h]);  // score bound

  // Q B-fragments: qf[c] = Q[r0+l15][c*32+quad*8+j]
  bf16x8 qf[4];
#pragma unroll
  for (int c = 0; c < 4; ++c)
    qf[c] = *(const bf16x8*)(Qb + (long)(r0 + l15) * HD + c * 32 + quad * 8);

  f32x4 zero = {0.f, 0.f, 0.f, 0.f};
  f32x4 acc[8];
#pragma unroll
  for (int d = 0; d < 8; ++d) acc[d] = zero;
  float lac = 0.f;

  // staging: 4 K-rounds (16 rows each) + 4 V-rounds (32 d-rows each), 4KB/round
  int ksrc[4], vsrc[4];
#pragma unroll
  for (int j = 0; j < 4; ++j) {
    int kr = j * 16 + (t >> 4);       // key-row 0..63
    ksrc[j] = kr * HD + (((t & 15) ^ (kr & 15)) << 3);
    int vd = j * 32 + (t >> 3);       // d-row 0..127
    vsrc[j] = vd * S_LEN + (((t & 7) ^ (vd & 7)) << 3);
  }

  const int kstart = (t0 >= WIN) ? (t0 - WIN) : 0;
  const int ntiles = (t0 + 64 - kstart) >> 6;

  for (int it = 0; it < ntiles; ++it) {
    const int kt = kstart + it * 64;
#pragma unroll
    for (int j = 0; j < 4; ++j) {
      async_load16(Kb + (long)kt * HD + ksrc[j], (char*)Ks + j * 4096 + t * 16);
      async_load16(Vb + kt + vsrc[j], (char*)Vs + j * 4096 + t * 16);
    }
    __syncthreads();  // drain staging

    if (kt <= r0 + 15 && kt + 63 >= r0 - (WIN - 1)) {
      // S^T = K·Q^T: lane q = l15, keys = kti*16 + quad*4 + r (consecutive)
#pragma unroll
      for (int kti = 0; kti < 4; ++kti) {
        bf16x8 kf[4];
#pragma unroll
        for (int c = 0; c < 4; ++c)
          kf[c] = *(const bf16x8*)(Ks + (kti * 16 + l15) * 128 +
                                   ((((c << 2) + quad) ^ l15) << 3));
        f32x4 sc = zero;
#pragma unroll
        for (int c = 0; c < 4; ++c)
          sc = __builtin_amdgcn_mfma_f32_16x16x32_bf16(kf[c], qf[c], sc, 0, 0, 0);
        const int qg = r0 + l15;
        const int kbase = kt + kti * 16 + quad * 4;
        bf16x4 pv;
#pragma unroll
        for (int r = 0; r < 4; ++r) {
          int key = kbase + r;
          float p = (key <= qg && key >= qg - (WIN - 1)) ? __expf(sc[r] - M) : 0.f;
          lac += p;
          pv[r] = (__bf16)p;
        }
        const int cb = kti * 4 + quad;  // 8B-chunk index 0..15
        *(bf16x4*)(&Ps[wid][l15 * 64 + ((cb ^ l15) << 2)]) = pv;
      }
      // P A-fragments + PV
      bf16x8 pf[2];
#pragma unroll
      for (int kc = 0; kc < 2; ++kc) {
        U8 u;
        u.h[0] = *(const bf16x4*)(&Ps[wid][l15 * 64 + (((kc * 8 + quad * 2) ^ l15) << 2)]);
        u.h[1] = *(const bf16x4*)(&Ps[wid][l15 * 64 + (((kc * 8 + quad * 2 + 1) ^ l15) << 2)]);
        pf[kc] = u.v;
      }
#pragma unroll
      for (int dt = 0; dt < 8; ++dt)
#pragma unroll
        for (int kc = 0; kc < 2; ++kc) {
          bf16x8 vf = *(const bf16x8*)(Vs + (dt * 16 + l15) * 64 +
                                       ((((kc << 2) + quad) ^ (l15 & 7)) << 3));
          acc[dt] = __builtin_amdgcn_mfma_f32_16x16x32_bf16(pf[kc], vf, acc[dt], 0, 0, 0);
        }
    }
    __syncthreads();  // protect single buffer before next staging
  }

  // epilogue: reduce l across quads (same l15 = same q), broadcast via shfl
  float s = lac;
  s += __shfl_xor(s, 16, 64);
  s += __shfl_xor(s, 32, 64);  // now every lane has l(q = its l15)
  __bf16* Yb = Y + ((long)b * S_LEN) * DIM + h * HD;
#pragma unroll
  for (int r = 0; r < 4; ++r) {
    const int row = quad * 4 + r;
    float il = 1.f / __shfl(s, row, 64);  // lane 'row' has l15==row
#pragma unroll
    for (int dt = 0; dt < 8; ++dt)
      Yb[(long)(r0 + row) * DIM + dt * 16 + l15] = (__bf16)(acc[dt][r] * il);
  }
}

// ---------------- launch ----------------
extern "C" void kernel_launch(void* const* d_in, const int* in_sizes, int n_in,
                              void* d_out, int out_size, void* d_ws, size_t ws_size,
                              hipStream_t stream) {
  (void)in_sizes; (void)n_in; (void)out_size; (void)ws_size;
  const float* x  = (const float*)d_in[0];
  const float* Wq = (const float*)d_in[1];
  const float* Wk = (const float*)d_in[2];
  const float* Wv = (const float*)d_in[3];
  const float* Wo = (const float*)d_in[4];
  const float* qg = (const float*)d_in[5];
  float* out = (float*)d_out;

  char* ws = (char*)d_ws;
  size_t off = 0;
  auto alloc = [&](size_t bytes) -> void* {
    void* p = ws + off;
    off += (bytes + 255) & ~(size_t)255;
    return p;
  };
  __bf16* xb   = (__bf16*)alloc(8388608ull * 2);      // x bf16; reused as yb
  __bf16* wqkv = (__bf16*)alloc(3072ull * 2048 * 2);  // permuted q/k weight rows
  __bf16* wob  = (__bf16*)alloc(2048ull * 2048 * 2);
  __bf16* qo   = (__bf16*)alloc((size_t)BATCH * NH * S_LEN * HD * 2);
  __bf16* ko   = (__bf16*)alloc((size_t)BATCH * NKV * S_LEN * HD * 2);
  __bf16* vt   = (__bf16*)alloc((size_t)BATCH * NKV * HD * S_LEN * 2);
  float*  cosT = (float*)alloc(2048ull * 64 * 4);
  float*  sinT = (float*)alloc(2048ull * 64 * 4);
  __bf16* yb   = xb;

  preprocess_kernel<<<18944, 256, 0, stream>>>(x, Wq, Wk, Wv, Wo, xb, wqkv, wob,
                                               cosT, sinT);
  gemm_qkv<<<dim3(32, 24), 256, 0, stream>>>(xb, wqkv, qg, cosT, sinT, qo, ko, vt);
  attn_kernel<<<dim3(32, 16, 2), 256, 0, stream>>>(qo, ko, vt, qg, yb);
  gemm_bt<<<dim3(32, 16), 256, 0, stream>>>(yb, wob, out, 4096, 2048, 2048);
}